// Round 1
// baseline (487.478 us; speedup 1.0000x reference)
//
#include <hip/hip_runtime.h>
#include <cstdint>

#define BB 8
#define CC 128
#define HH 96
#define WW 160
#define HWsz (HH * WW)            // 15360
#define TH 8
#define TW 32
#define CSTEP 8
#define HALO_H 16                 // TH + 8
#define SW 64                     // padded halo row stride in words (48 staged, 40 logically used)
#define CI_WORDS (HALO_H * SW)    // 1024 words = 4 KB per channel slice
#define BUF_WORDS (CSTEP * CI_WORDS) // 8192 words = 32 KB per buffer
#define NWAVES 9
#define NTHREADS (NWAVES * 64)    // 576
#define NSLOTS (CSTEP * HALO_H)   // 128 staged (ci,row) slots per chunk
#define NCHUNKS (CC / CSTEP)      // 16
#define NBLOCKS (BB * (HH / TH) * (WW / TW))  // 480

__device__ __forceinline__ void g2l_dword(const float* g, float* l) {
  __builtin_amdgcn_global_load_lds((const __attribute__((address_space(1))) void*)g,
                                   (__attribute__((address_space(3))) void*)l,
                                   4, 0, 0);
}

// Stage one 8-channel chunk's halo (16 rows x 48 cols per channel) into LDS.
// LDS dest is linear (global_load_lds requirement); the 16B-block XOR swizzle
// (col ^ ((row&3)<<2)) is applied by permuting the *global source* column, so
// source-permutation and read-side swizzle are the same involution.
// slot math is wave-uniform (wvu is readfirstlane'd) -> scalar ops.
__device__ __forceinline__ void stage_chunk(const float* __restrict__ src, float* dst,
                                            int h0, int w0, int lane, int wvu) {
  for (int slot = wvu; slot < NSLOTS; slot += NWAVES) {   // uniform trip count
    const int ci  = slot >> 4;
    const int row = slot & 15;
    int gh = h0 + row - 4; gh = gh < 0 ? 0 : (gh > HH - 1 ? HH - 1 : gh);
    const int cl = lane ^ ((row & 3) << 2);   // logical halo col for this phys slot
    int gw = w0 + cl - 4; gw = gw < 0 ? 0 : (gw > WW - 1 ? WW - 1 : gw);
    if (lane < 48)                            // cols 48..63 of the padded row unused
      g2l_dword(src + (ci * HH + gh) * WW + gw, dst + ci * CI_WORDS + row * SW);
  }
}

// launch_bounds(576,5): 2 blocks/CU needs 18 waves -> max 5 waves/SIMD -> VGPR<=102.
// acc[9][8]=72 persistent; keep transients (av8+w16) tight. Known-fatal failure
// mode (R2/R3): acc spill to scratch -> check VGPR/scratch in counters.
extern "C" __global__ void __launch_bounds__(NTHREADS, 5)
corr81_kernel(const float* __restrict__ x1, const float* __restrict__ x2,
              float* __restrict__ out)
{
  __shared__ __align__(16) float lds[2][BUF_WORDS];  // 64 KB total (2 blocks/CU = 128 KB)

  const int tid  = threadIdx.x;
  const int wv   = tid >> 6;     // dy index 0..8 (wave-uniform)
  const int wvu  = __builtin_amdgcn_readfirstlane(wv);
  const int lane = tid & 63;
  const int h    = lane >> 5;        // channel-half: ci = 4h..4h+3 of the chunk
  const int r    = (lane >> 2) & 7;  // tile row 0..7
  const int s    = lane & 3;         // 8-px col slot (cols 8s..8s+7)

  // XCD-bijective swizzle: 480 % 8 == 0; each XCD gets 60 consecutive logical
  // tiles = exactly one image b -> all halo re-reads stay in one XCD's L2.
  const int bid0 = blockIdx.x;
  const int bid  = (bid0 & 7) * (NBLOCKS / 8) + (bid0 >> 3);

  const int wt = bid % (WW / TW);
  const int ht = (bid / (WW / TW)) % (HH / TH);
  const int b  = bid / ((WW / TW) * (HH / TH));
  const int h0 = ht * TH;
  const int w0 = wt * TW;

  // x2 LDS read bases (word offsets): 4 regs, ci & buffer selected by immediates/flip.
  const int R  = r + wv;             // halo row this lane reads (0..15)
  const int fx = (R & 3) << 2;       // word-level XOR field, matches staging swizzle
  int A[4];
#pragma unroll
  for (int t = 0; t < 4; ++t)
    A[t] = h * 4096 + R * SW + ((8 * s + 4 * t) ^ fx);

  const float* x2b = x2 + (size_t)b * CC * HWsz;
  const float* x1p = x1 + ((size_t)b * CC + 4 * h) * HWsz
                        + (size_t)(h0 + r) * WW + (w0 + 8 * s);

  float acc[9][8];
#pragma unroll
  for (int d = 0; d < 9; ++d)
#pragma unroll
    for (int p = 0; p < 8; ++p) acc[d][p] = 0.f;

  // prologue: stage chunk 0 into buffer 0
  stage_chunk(x2b, &lds[0][0], h0, w0, lane, wvu);
  __syncthreads();

#pragma unroll 1
  for (int chunk = 0; chunk < NCHUNKS; ++chunk) {
    if (chunk + 1 < NCHUNKS)
      stage_chunk(x2b + (size_t)(chunk + 1) * (CSTEP * HWsz),
                  &lds[(chunk + 1) & 1][0], h0, w0, lane, wvu);

    const float* lb = &lds[0][0];
#pragma unroll
    for (int q = 0; q < 4; ++q) {          // ci = 4h + q
      const float* x1q = x1p + (size_t)q * HWsz;
      const float4 a0 = ((const float4*)x1q)[0];
      const float4 a1 = ((const float4*)x1q)[1];
      const float av[8] = {a0.x, a0.y, a0.z, a0.w, a1.x, a1.y, a1.z, a1.w};
      float w16[16];
#pragma unroll
      for (int t = 0; t < 4; ++t) {        // 4 x ds_read_b128, offsets all-immediate
        const float4 f = *(const float4*)(lb + A[t] + q * 1024);
        w16[4*t+0] = f.x; w16[4*t+1] = f.y; w16[4*t+2] = f.z; w16[4*t+3] = f.w;
      }
#pragma unroll
      for (int d = 0; d < 9; ++d)
#pragma unroll
        for (int p = 0; p < 8; ++p)
          acc[d][p] = fmaf(av[p], w16[d + p], acc[d][p]);
    }

    x1p += (size_t)CSTEP * HWsz;
    const int flip = (chunk & 1) ? -BUF_WORDS : BUF_WORDS;  // ping-pong read base
    A[0] += flip; A[1] += flip; A[2] += flip; A[3] += flip;
    __syncthreads();   // one barrier per chunk; vmcnt(0) drain covered by compute
  }

  // epilogue: combine the two channel-halves across lane^32, scale by 1/8, store.
  // h=0 lane owns px 0..3, h=1 owns px 4..7; send the half the partner owns.
  float* op = out + (((size_t)b * 81 + (size_t)wv * 9) * HH + (h0 + r)) * WW
                  + (w0 + 8 * s + 4 * h);
#pragma unroll
  for (int d = 0; d < 9; ++d) {
    const float own0 = h ? acc[d][4] : acc[d][0];
    const float own1 = h ? acc[d][5] : acc[d][1];
    const float own2 = h ? acc[d][6] : acc[d][2];
    const float own3 = h ? acc[d][7] : acc[d][3];
    const float snd0 = h ? acc[d][0] : acc[d][4];
    const float snd1 = h ? acc[d][1] : acc[d][5];
    const float snd2 = h ? acc[d][2] : acc[d][6];
    const float snd3 = h ? acc[d][3] : acc[d][7];
    float4 v;
    v.x = (own0 + __shfl_xor(snd0, 32)) * 0.125f;
    v.y = (own1 + __shfl_xor(snd1, 32)) * 0.125f;
    v.z = (own2 + __shfl_xor(snd2, 32)) * 0.125f;
    v.w = (own3 + __shfl_xor(snd3, 32)) * 0.125f;
    *(float4*)(op + (size_t)d * HWsz) = v;
  }
}

extern "C" void kernel_launch(void* const* d_in, const int* in_sizes, int n_in,
                              void* d_out, int out_size, void* d_ws, size_t ws_size,
                              hipStream_t stream) {
  const float* x1 = (const float*)d_in[0];
  const float* x2 = (const float*)d_in[1];
  float* out = (float*)d_out;
  corr81_kernel<<<dim3(NBLOCKS), dim3(NTHREADS), 0, stream>>>(x1, x2, out);
}

// Round 2
// 248.632 us; speedup vs baseline: 1.9606x; 1.9606x over previous
//
#include <hip/hip_runtime.h>
#include <cstdint>

#define BB 8
#define CC 128
#define HH 96
#define WW 160
#define HWsz (HH * WW)            // 15360
#define TH 8
#define TW 32
#define CSTEP 8
#define HALO_H 16                 // TH + 8
#define SW 48                     // padded halo row stride in words = 12 four-word blocks
#define CI_WORDS (HALO_H * SW)    // 768 words = 3 KB per channel slice
#define BUF_WORDS (CSTEP * CI_WORDS) // 6144 words = 24 KB per buffer
#define NWAVES 9
#define NTHREADS (NWAVES * 64)    // 576
#define NSLOTS (CSTEP * HALO_H)   // 128 staged (ci,row) slots per chunk
#define NCHUNKS (CC / CSTEP)      // 16
#define NBLOCKS (BB * (HH / TH) * (WW / TW))  // 480

__device__ __forceinline__ void g2l_dword(const float* g, float* l) {
  __builtin_amdgcn_global_load_lds((const __attribute__((address_space(1))) void*)g,
                                   (__attribute__((address_space(3))) void*)l,
                                   4, 0, 0);
}

// Stage one 8-channel chunk's halo (16 rows x 48 cols per channel) into LDS.
// LDS dest is linear (global_load_lds requirement); the 4-word-block XOR swizzle
// (block ^ (row&3)) is applied by permuting the *global source* column, so the
// source permutation and the read-side swizzle are the same involution.
// Validated in R1 (passed correctness; conflicts 3x down). Only SW changed 64->48.
__device__ __forceinline__ void stage_chunk(const float* __restrict__ src, float* dst,
                                            int h0, int w0, int lane, int wvu) {
  for (int slot = wvu; slot < NSLOTS; slot += NWAVES) {   // wave-uniform trip count
    const int ci  = slot >> 4;
    const int row = slot & 15;
    int gh = h0 + row - 4; gh = gh < 0 ? 0 : (gh > HH - 1 ? HH - 1 : gh);
    const int cl = lane ^ ((row & 3) << 2);   // logical halo col for this phys slot
    int gw = w0 + cl - 4; gw = gw < 0 ? 0 : (gw > WW - 1 ? WW - 1 : gw);
    if (lane < SW)                            // stage 12 blocks (reads touch blocks 0..11)
      g2l_dword(src + (ci * HH + gh) * WW + gw, dst + ci * CI_WORDS + row * SW);
  }
}

// launch_bounds(576,2): NO VGPR pressure (cap 256). R1 post-mortem: forcing the
// cap to 102 with acc[9][8]=72 spilled acc to scratch (VGPR=48, WRITE 460 MB,
// 3.5x regression). This round returns to the register-proven acc[9][4] shape
// (R0 compiled to 64 VGPR, zero spill) and keeps only the two validated wins:
// bank swizzle + XCD swizzle. Natural VGPR ~64-72 -> 7 waves/SIMD -> 3 blocks/CU
// (27 waves), and LDS 48 KB/block * 3 = 144 KB <= 160 KB.
extern "C" __global__ void __launch_bounds__(NTHREADS, 2)
corr81_kernel(const float* __restrict__ x1, const float* __restrict__ x2,
              float* __restrict__ out)
{
  __shared__ __align__(16) float lds[2][BUF_WORDS];  // ping-pong, 48 KB total

  const int tid  = threadIdx.x;
  const int wv   = tid >> 6;     // dy index 0..8 (wave-uniform)
  const int wvu  = __builtin_amdgcn_readfirstlane(wv);
  const int lane = tid & 63;
  const int r    = lane >> 3;    // tile row 0..7
  const int j    = lane & 7;     // w-slot 0..7 (4 px each)

  // XCD-bijective swizzle: 480 % 8 == 0; each XCD gets 60 consecutive logical
  // tiles = exactly one image b -> halo re-reads stay in that XCD's L2.
  // Validated in R1: FETCH 184 MB -> 85 MB.
  const int bid0 = blockIdx.x;
  const int bid  = (bid0 & 7) * (NBLOCKS / 8) + (bid0 >> 3);

  const int wt = bid % (WW / TW);
  const int ht = (bid / (WW / TW)) % (HH / TH);
  const int b  = bid / ((WW / TW) * (HH / TH));
  const int h0 = ht * TH;
  const int w0 = wt * TW;

  // x2 LDS read bases (word offsets). Bank check (within every 16-lane phase of
  // a b128): group = (16(R&1) + 4((j+t)^(R&3)))>>2 mod 8 is uniform (2 lanes per
  // 4-bank group per phase) -> zero excess conflict.
  const int R = r + wv;              // halo row this lane reads (0..15)
  const int m = R & 3;               // block-level XOR field, matches staging
  int A[3];
#pragma unroll
  for (int t = 0; t < 3; ++t)
    A[t] = R * SW + 4 * ((j + t) ^ m);

  const float* x2b = x2 + b * (CC * HWsz);
  const float* x1p = x1 + b * (CC * HWsz) + (h0 + r) * WW + (w0 + 4 * j);

  float acc[9][4];
#pragma unroll
  for (int d = 0; d < 9; ++d)
#pragma unroll
    for (int p = 0; p < 4; ++p) acc[d][p] = 0.f;

  // ---- prologue: stage chunk 0 into buffer 0
  stage_chunk(x2b, &lds[0][0], h0, w0, lane, wvu);
  __syncthreads();

  // ---- rolled ping-pong: stage(k+1) issued BEFORE compute(k); the single
  // barrier's vmcnt(0) drain is covered by compute + 2 other resident blocks.
#pragma unroll 1
  for (int chunk = 0; chunk < NCHUNKS; ++chunk) {
    if (chunk + 1 < NCHUNKS)
      stage_chunk(x2b + (chunk + 1) * (CSTEP * HWsz),
                  &lds[(chunk + 1) & 1][0], h0, w0, lane, wvu);

    const float* lb = &lds[0][0];
#pragma unroll
    for (int ci = 0; ci < CSTEP; ++ci) {
      const float4 a4 = *(const float4*)(x1p + ci * HWsz);
      const float av[4] = {a4.x, a4.y, a4.z, a4.w};
      float w12[12];
#pragma unroll
      for (int t = 0; t < 3; ++t) {        // 3 x ds_read_b128, ci/buffer in immediates
        const float4 f = *(const float4*)(lb + A[t] + ci * CI_WORDS);
        w12[4*t+0] = f.x; w12[4*t+1] = f.y; w12[4*t+2] = f.z; w12[4*t+3] = f.w;
      }
#pragma unroll
      for (int d = 0; d < 9; ++d)
#pragma unroll
        for (int p = 0; p < 4; ++p)
          acc[d][p] = fmaf(av[p], w12[d + p], acc[d][p]);
    }

    x1p += CSTEP * HWsz;
    const int flip = (chunk & 1) ? -BUF_WORDS : BUF_WORDS;  // ping-pong read base
    A[0] += flip; A[1] += flip; A[2] += flip;
    __syncthreads();   // one barrier per chunk
  }

  // epilogue: out[((b*81 + wv*9+d)*H + h0+r)*W + w0+4j ...], scale 1/8
  float* op = out + ((b * 81 + wv * 9) * HH + (h0 + r)) * WW + (w0 + 4 * j);
#pragma unroll
  for (int d = 0; d < 9; ++d) {
    float4 v;
    v.x = acc[d][0] * 0.125f;
    v.y = acc[d][1] * 0.125f;
    v.z = acc[d][2] * 0.125f;
    v.w = acc[d][3] * 0.125f;
    *(float4*)(op + d * HWsz) = v;
  }
}

extern "C" void kernel_launch(void* const* d_in, const int* in_sizes, int n_in,
                              void* d_out, int out_size, void* d_ws, size_t ws_size,
                              hipStream_t stream) {
  const float* x1 = (const float*)d_in[0];
  const float* x2 = (const float*)d_in[1];
  float* out = (float*)d_out;
  corr81_kernel<<<dim3(NBLOCKS), dim3(NTHREADS), 0, stream>>>(x1, x2, out);
}

// Round 3
// 210.193 us; speedup vs baseline: 2.3192x; 1.1829x over previous
//
#include <hip/hip_runtime.h>
#include <cstdint>

#define BB 8
#define CC 128
#define HH 96
#define WW 160
#define HWsz (HH * WW)                 // 15360
#define TH 8
#define TW 32
#define CSTEP 8
#define HALO_H 16                      // TH + 8
#define HALO_W 40                      // TW + 8
#define CH_WORDS (HALO_H * HALO_W)     // 640
#define X2_WORDS (CSTEP * CH_WORDS)    // 5120 words = 20 KB per buffer
#define X1_WORDS (CSTEP * TH * TW)     // 2048 words = 8 KB per buffer
#define X2_SLOTS (X2_WORDS / 64)       // 80 wave-sized dword loads
#define X1_SLOTS (X1_WORDS / 64)       // 32
#define NWAVES 9
#define NTHREADS (NWAVES * 64)         // 576
#define NCHUNKS (CC / CSTEP)           // 16
#define NBLOCKS (BB * (HH / TH) * (WW / TW))  // 480
#define X1BASE (2 * X2_WORDS)          // LDS word map: x2@0,5120; x1@10240,12288; 56 KB total

__device__ __forceinline__ void g2l_dword(const float* g, float* l) {
  __builtin_amdgcn_global_load_lds((const __attribute__((address_space(1))) void*)g,
                                   (__attribute__((address_space(3))) void*)l,
                                   4, 0, 0);
}

// Structure (R3): 2-deep ping-pong for BOTH x2-halo and x1-tile, ALL loads are
// global_load_lds with chunk-invariant precomputed offsets (R2 lesson: per-chunk
// address recompute in a dynamic loop cost ~40 us). No global loads inside the
// compute body -> no compiler-inserted vmcnt waits can drain the prefetch; the
// ONLY waits are our counted s_waitcnt vmcnt(13) (T4). Two raw barriers/chunk.
//
// Safety proof sketch:
//  iter k: [A: issue stage(k+1) 13 loads][B: vmcnt(13)][C: s_barrier]
//          [D: compute(k)][C2: s_barrier]
//  RAW: B drains everything older than stage(k+1) => this wave's stage(k) done;
//       C makes that true for all waves before any D(k) read.
//  WAR: A(k) writes buf((k+1)&1), last read by D(k-1); any wave at A(k) passed
//       C2(k-1), which required ALL waves to finish D(k-1). Max drift between
//       consecutive barriers is one phase, so no 3rd buffer needed.
extern "C" __global__ void __launch_bounds__(NTHREADS, 2)
corr81_kernel(const float* __restrict__ x1, const float* __restrict__ x2,
              float* __restrict__ out)
{
  __shared__ __align__(16) float lds[2 * X2_WORDS + 2 * X1_WORDS];  // 56 KB

  const int tid  = threadIdx.x;
  const int wv   = tid >> 6;                              // dy 0..8 (wave-uniform)
  const int wvu  = __builtin_amdgcn_readfirstlane(wv);    // SGPR copy for slot math
  const int lane = tid & 63;
  const int r    = lane >> 3;    // tile row 0..7
  const int j    = lane & 7;     // w-slot 0..7 (4 px each)

  // XCD-bijective swizzle (validated R1/R2: FETCH 184->65..85 MB). 480 % 8 == 0;
  // each XCD owns 60 consecutive tiles = one image b -> halo re-reads L2-local.
  const int bid0 = blockIdx.x;
  const int bid  = (bid0 & 7) * (NBLOCKS / 8) + (bid0 >> 3);

  const int wt = bid % (WW / TW);
  const int ht = (bid / (WW / TW)) % (HH / TH);
  const int b  = bid / ((WW / TW) * (HH / TH));
  const int h0 = ht * TH;
  const int w0 = wt * TW;

  // ---- chunk-invariant staging offsets, computed ONCE (R0 scheme).
  // x2 halo: 80 slots, slot idx = wvu + 9*i; idx 80 clamps to 79 (benign dup:
  // same source word -> same LDS word, same data).
  uint32_t soff2[9]; uint32_t doff2[9];
#pragma unroll
  for (int i = 0; i < 9; ++i) {
    int idx = wvu + 9 * i; if (idx >= X2_SLOTS) idx = X2_SLOTS - 1;
    const int e   = idx * 64 + lane;
    const int ci  = e / CH_WORDS;
    const int rem = e - ci * CH_WORDS;
    const int hr  = rem / HALO_W;
    const int wh  = rem - hr * HALO_W;
    int gh = h0 + hr - 4; gh = gh < 0 ? 0 : (gh > HH - 1 ? HH - 1 : gh);
    int gw = w0 + wh - 4; gw = gw < 0 ? 0 : (gw > WW - 1 ? WW - 1 : gw);
    soff2[i] = (uint32_t)((ci * HH + gh) * WW + gw);
    doff2[i] = (uint32_t)(idx * 64);                      // wave-uniform -> SGPR
  }
  // x1 tile: 32 slots (8ch x 8r x 32w, no halo/clamps), 4 per wave; idx>=32
  // clamps to 31 (benign dup). Staged ONCE per block instead of 9x per wave.
  uint32_t soff1[4]; uint32_t doff1[4];
#pragma unroll
  for (int i = 0; i < 4; ++i) {
    int idx = wvu + 9 * i; if (idx >= X1_SLOTS) idx = X1_SLOTS - 1;
    const int e   = idx * 64 + lane;
    const int ci  = e >> 8;
    const int rem = e & 255;
    const int row = rem >> 5;
    const int col = rem & 31;
    soff1[i] = (uint32_t)(ci * HWsz + (h0 + row) * WW + (w0 + col));
    doff1[i] = (uint32_t)(idx * 64);
  }

  const float* x2b = x2 + (size_t)b * CC * HWsz;
  const float* x1b = x1 + (size_t)b * CC * HWsz;

  float acc[9][4];
#pragma unroll
  for (int d = 0; d < 9; ++d)
#pragma unroll
    for (int p = 0; p < 4; ++p) acc[d][p] = 0.f;

  const int rowbase = (r + wv) * HALO_W + 4 * j;   // x2 LDS read base (words)
  const int abase   = r * TW + 4 * j;              // x1 LDS read base (words)

  // ---- prologue: stage chunk 0 into half 0 (13 loads/wave)
#pragma unroll
  for (int i = 0; i < 9; ++i) g2l_dword(x2b + soff2[i], &lds[doff2[i]]);
#pragma unroll
  for (int i = 0; i < 4; ++i) g2l_dword(x1b + soff1[i], &lds[X1BASE + doff1[i]]);

#pragma unroll 1
  for (int k = 0; k < NCHUNKS - 1; ++k) {
    // [A] issue stage(k+1) into half (k+1)&1 — 13 loads, all-unrolled, no addr math
    {
      const int nb = (k + 1) & 1;
      const float* s2 = x2b + (size_t)(k + 1) * (CSTEP * HWsz);
      const float* s1 = x1b + (size_t)(k + 1) * (CSTEP * HWsz);
      float* d2 = &lds[nb * X2_WORDS];
      float* d1 = &lds[X1BASE + nb * X1_WORDS];
#pragma unroll
      for (int i = 0; i < 9; ++i) g2l_dword(s2 + soff2[i], d2 + doff2[i]);
#pragma unroll
      for (int i = 0; i < 4; ++i) g2l_dword(s1 + soff1[i], d1 + doff1[i]);
    }

    // [B] counted wait: keep stage(k+1)'s 13 in flight, guarantee stage(k) done
    asm volatile("s_waitcnt vmcnt(13)" ::: "memory");
    __builtin_amdgcn_sched_barrier(0);
    // [C]
    __builtin_amdgcn_s_barrier();
    __builtin_amdgcn_sched_barrier(0);

    // [D] compute chunk k from half k&1 — pure LDS + FMA, zero vmem
    {
      const float* xb = &lds[(k & 1) * X2_WORDS] + rowbase;
      const float* ab = &lds[X1BASE + (k & 1) * X1_WORDS] + abase;
#pragma unroll
      for (int ci = 0; ci < CSTEP; ++ci) {
        const float4 a4 = *(const float4*)(ab + ci * (TH * TW));
        const float4* wr = (const float4*)(xb + ci * CH_WORDS);
        const float4 f0 = wr[0];
        const float4 f1 = wr[1];
        const float4 f2 = wr[2];
        const float av[4] = {a4.x, a4.y, a4.z, a4.w};
        const float w12[12] = {f0.x, f0.y, f0.z, f0.w,
                               f1.x, f1.y, f1.z, f1.w,
                               f2.x, f2.y, f2.z, f2.w};
#pragma unroll
        for (int d = 0; d < 9; ++d)
#pragma unroll
          for (int p = 0; p < 4; ++p)
            acc[d][p] = fmaf(av[p], w12[d + p], acc[d][p]);
      }
    }

    // [C2]
    __builtin_amdgcn_sched_barrier(0);
    __builtin_amdgcn_s_barrier();
    __builtin_amdgcn_sched_barrier(0);
  }

  // ---- peeled last chunk (k = 15, half 1): nothing left to prefetch
  asm volatile("s_waitcnt vmcnt(0)" ::: "memory");
  __builtin_amdgcn_sched_barrier(0);
  __builtin_amdgcn_s_barrier();
  __builtin_amdgcn_sched_barrier(0);
  {
    const int k = NCHUNKS - 1;
    const float* xb = &lds[(k & 1) * X2_WORDS] + rowbase;
    const float* ab = &lds[X1BASE + (k & 1) * X1_WORDS] + abase;
#pragma unroll
    for (int ci = 0; ci < CSTEP; ++ci) {
      const float4 a4 = *(const float4*)(ab + ci * (TH * TW));
      const float4* wr = (const float4*)(xb + ci * CH_WORDS);
      const float4 f0 = wr[0];
      const float4 f1 = wr[1];
      const float4 f2 = wr[2];
      const float av[4] = {a4.x, a4.y, a4.z, a4.w};
      const float w12[12] = {f0.x, f0.y, f0.z, f0.w,
                             f1.x, f1.y, f1.z, f1.w,
                             f2.x, f2.y, f2.z, f2.w};
#pragma unroll
      for (int d = 0; d < 9; ++d)
#pragma unroll
        for (int p = 0; p < 4; ++p)
          acc[d][p] = fmaf(av[p], w12[d + p], acc[d][p]);
    }
  }

  // epilogue: out[((b*81 + wv*9+d)*H + h0+r)*W + w0+4j ...], scale 1/8
  float* op = out + (((size_t)b * 81 + (size_t)wv * 9) * HH + (h0 + r)) * WW + (w0 + 4 * j);
#pragma unroll
  for (int d = 0; d < 9; ++d) {
    float4 v;
    v.x = acc[d][0] * 0.125f;
    v.y = acc[d][1] * 0.125f;
    v.z = acc[d][2] * 0.125f;
    v.w = acc[d][3] * 0.125f;
    *(float4*)(op + (size_t)d * HWsz) = v;
  }
}

extern "C" void kernel_launch(void* const* d_in, const int* in_sizes, int n_in,
                              void* d_out, int out_size, void* d_ws, size_t ws_size,
                              hipStream_t stream) {
  const float* x1 = (const float*)d_in[0];
  const float* x2 = (const float*)d_in[1];
  float* out = (float*)d_out;
  corr81_kernel<<<dim3(NBLOCKS), dim3(NTHREADS), 0, stream>>>(x1, x2, out);
}